// Round 3
// baseline (83670.483 us; speedup 1.0000x reference)
//
#include <hip/hip_runtime.h>
#include <hip/hip_cooperative_groups.h>

namespace cg = cooperative_groups;

typedef __bf16 bf16x8 __attribute__((ext_vector_type(8)));
typedef __bf16 bf16x4 __attribute__((ext_vector_type(4)));
typedef float  f32x4  __attribute__((ext_vector_type(4)));

#define MFMA(a, b, c) __builtin_amdgcn_mfma_f32_16x16x32_bf16((a), (b), (c), 0, 0, 0)

#define B_   8
#define S_   2048
#define SP_  128        // steps per phase
#define NP_  16         // phases
#define D_   1024
#define G4_  4096       // 4*D

// d_out ELEMENT offsets (f32 out)
#define OQ_OFF  0ul
#define OK_OFF  16777216ul
#define HQ_OFF  20971520ul
#define CQ_OFF  20979712ul
#define HK_OFF  20987904ul
#define CK_OFF  20996096ul

__device__ __forceinline__ float sigm(float x) { return 1.0f / (1.0f + __expf(-x)); }
__device__ __forceinline__ float tanhf_(float x) { return 1.0f - 2.0f / (1.0f + __expf(2.0f * x)); }

__device__ __forceinline__ bf16x8 cvt8(float4 a, float4 b) {
  bf16x8 r;
  r[0] = (__bf16)a.x; r[1] = (__bf16)a.y; r[2] = (__bf16)a.z; r[3] = (__bf16)a.w;
  r[4] = (__bf16)b.x; r[5] = (__bf16)b.y; r[6] = (__bf16)b.z; r[7] = (__bf16)b.w;
  return r;
}

// ---------------------------------------------------------------------------
// f32 -> bf16 cast (grid-stride)
// ---------------------------------------------------------------------------
__global__ void cast_bf16(const float* __restrict__ src, __bf16* __restrict__ dst, int n) {
  int i = blockIdx.x * 256 + threadIdx.x;
  const int stride = gridDim.x * 256;
  for (; i < n; i += stride) dst[i] = (__bf16)src[i];
}

// ---------------------------------------------------------------------------
// Init: seed h-carry (H row SP-1 per batch, bf16) and c-carry (f32).
// ---------------------------------------------------------------------------
__global__ void init_carry(const float* __restrict__ hq0, const float* __restrict__ cq0,
                           const float* __restrict__ hk0, const float* __restrict__ ck0,
                           __bf16* __restrict__ Hq, __bf16* __restrict__ Hk,
                           float* __restrict__ Cc) {
  const int idx  = blockIdx.x * 256 + threadIdx.x;   // 0..16383
  const int cell = idx >> 13;
  const int rem  = idx & 8191;
  const int b    = rem >> 10;
  const int d    = rem & 1023;
  const float* h0 = cell ? hk0 : hq0;
  const float* c0 = cell ? ck0 : cq0;
  __bf16* H       = cell ? Hk  : Hq;
  H[((size_t)b * SP_ + (SP_ - 1)) * D_ + d] = (__bf16)h0[(size_t)b * D_ + d];
  Cc[(size_t)cell * 8192 + b * 1024 + d]    = c0[(size_t)b * D_ + d];
}

// ---------------------------------------------------------------------------
// Kernel 1: phase gx = x_phase @ Wi^T + (bi + bh), both cells (blockIdx.z).
// f32 inputs, converted to bf16 during manual LDS staging. m97 MFMA core.
// Phase-local rows: r = b*128 + sl  ->  X row b*2048 + s0 + sl.
// ---------------------------------------------------------------------------
__global__ __launch_bounds__(256, 2) void gemm_gx(
    const float* __restrict__ X, int s0,
    const float* __restrict__ Wq, const float* __restrict__ biq, const float* __restrict__ bhq,
    const float* __restrict__ Wk, const float* __restrict__ bik, const float* __restrict__ bhk,
    __bf16* __restrict__ GXq, __bf16* __restrict__ GXk)
{
  const float* W;  const float* bi;  const float* bh;  __bf16* GX;
  if (blockIdx.z == 0) { W = Wq; bi = biq; bh = bhq; GX = GXq; }
  else                 { W = Wk; bi = bik; bh = bhk; GX = GXk; }

  const int m0 = blockIdx.y * 128;                 // phase-local row tile (one batch slice)
  const int n0 = blockIdx.x * 128;
  const int xrow0 = (m0 >> 7) * S_ + s0;           // 128 rows contiguous in X

  __shared__ __align__(16) __bf16 As[128 * 32];
  __shared__ __align__(16) __bf16 Bs[128 * 32];

  const int t    = threadIdx.x;
  const int wave = t >> 6;
  const int lane = t & 63;
  const int quad = lane >> 4;
  const int l16  = lane & 15;
  const int srow = t >> 1;          // 0..127
  const int scol = (t & 1) * 16;    // 0 or 16
  const int wm = wave & 1, wn = wave >> 1;

  f32x4 acc[4][4];
#pragma unroll
  for (int i = 0; i < 4; ++i)
#pragma unroll
    for (int j = 0; j < 4; ++j) acc[i][j] = (f32x4){0.f, 0.f, 0.f, 0.f};

  for (int kk = 0; kk < 1024; kk += 32) {
    const float* ga = X + (size_t)(xrow0 + srow) * 1024 + kk + scol;
    const float* gb = W + (size_t)(n0 + srow) * 1024 + kk + scol;
    const float4 va0 = *(const float4*)(ga);     const float4 va1 = *(const float4*)(ga + 4);
    const float4 va2 = *(const float4*)(ga + 8); const float4 va3 = *(const float4*)(ga + 12);
    const float4 vb0 = *(const float4*)(gb);     const float4 vb1 = *(const float4*)(gb + 4);
    const float4 vb2 = *(const float4*)(gb + 8); const float4 vb3 = *(const float4*)(gb + 12);
    __syncthreads();   // previous iteration's fragment reads complete
    *(bf16x8*)&As[srow * 32 + scol]     = cvt8(va0, va1);
    *(bf16x8*)&As[srow * 32 + scol + 8] = cvt8(va2, va3);
    *(bf16x8*)&Bs[srow * 32 + scol]     = cvt8(vb0, vb1);
    *(bf16x8*)&Bs[srow * 32 + scol + 8] = cvt8(vb2, vb3);
    __syncthreads();

    bf16x8 af[4], bfq[4];
#pragma unroll
    for (int i = 0; i < 4; ++i) af[i]  = *(const bf16x8*)&As[(wm * 64 + i * 16 + l16) * 32 + quad * 8];
#pragma unroll
    for (int j = 0; j < 4; ++j) bfq[j] = *(const bf16x8*)&Bs[(wn * 64 + j * 16 + l16) * 32 + quad * 8];
#pragma unroll
    for (int i = 0; i < 4; ++i)
#pragma unroll
      for (int j = 0; j < 4; ++j)
        acc[i][j] = MFMA(af[i], bfq[j], acc[i][j]);
  }

#pragma unroll
  for (int j = 0; j < 4; ++j) {
    const int n = n0 + wn * 64 + j * 16 + l16;
    const float bias = bi[n] + bh[n];
#pragma unroll
    for (int i = 0; i < 4; ++i) {
#pragma unroll
      for (int r = 0; r < 4; ++r) {
        const int m = m0 + wm * 64 + i * 16 + quad * 4 + r;   // phase-local row
        GX[(size_t)m * G4_ + n] = (__bf16)(acc[i][j][r] + bias);
      }
    }
  }
}

// ---------------------------------------------------------------------------
// Kernel 2: one phase (128 steps) of the recurrence. 128 WGs x 256 thr.
// WG = (cell, 16 hidden dims); wave = gate type; Wh fragments in VGPRs.
// h-carry enters via H row SP-1 (bf16); c-carry via f32 Cc buffer.
// ---------------------------------------------------------------------------
__global__ __launch_bounds__(256, 1) void lstm_rec(
    const __bf16* __restrict__ GXq, const __bf16* __restrict__ GXk,
    const __bf16* __restrict__ Whq, const __bf16* __restrict__ Whk,
    __bf16* __restrict__ Hq, __bf16* __restrict__ Hk,
    float* __restrict__ Cc, float* __restrict__ dout, int last)
{
  const int wg   = blockIdx.x;           // 0..127
  const int cell = wg >> 6;
  const int ds   = (wg & 63) * 16;       // hidden-dim base
  const int t0   = threadIdx.x;
  const int wave = t0 >> 6;              // gate type: 0=i 1=f 2=g 3=o
  const int lane = t0 & 63;
  const int quad = lane >> 4;
  const int l16  = lane & 15;
  const int b    = l16 & 7;              // batch (cols 8..15 duplicate 0..7)

  const __bf16* GX = cell ? GXk : GXq;
  const __bf16* Wh = cell ? Whk : Whq;
  __bf16* H        = cell ? Hk  : Hq;
  float* cc        = Cc + (size_t)cell * 8192;
  const size_t hoff = cell ? HK_OFF : HQ_OFF;
  const size_t coff = cell ? CK_OFF : CQ_OFF;

  const int gbase = wave * 1024 + ds;    // gate-row base in the 4096 block

  // A-fragments of Wh (bf16), register-resident: A[m=l16][k=quad*8+j].
  bf16x8 wf[32];
#pragma unroll
  for (int kk = 0; kk < 32; ++kk)
    wf[kk] = *(const bf16x8*)&Wh[(size_t)(gbase + l16) * 1024 + kk * 32 + quad * 8];

  __shared__ float gbuf[4][16][16];
  __shared__ float cst[16][8];
  if (t0 < 128) {
    const int d = t0 >> 3, bb = t0 & 7;
    cst[d][bb] = cc[(size_t)bb * 1024 + ds + d];
  }
  __syncthreads();

  const __bf16* gxlane = GX + (size_t)b * SP_ * G4_ + gbase + quad * 4;
  bf16x4 gxn = *(const bf16x4*)(gxlane);

  cg::grid_group grid = cg::this_grid();

  for (int t = 0; t < SP_; ++t) {
    const bf16x4 gxc = gxn;
    if (t < SP_ - 1) gxn = *(const bf16x4*)(gxlane + (size_t)(t + 1) * G4_);

    // B-fragments: B[k][n] = h_prev[b][k]; t==0 reads carry row SP-1.
    const __bf16* hsrc = H + ((size_t)b * SP_ + ((t == 0) ? (SP_ - 1) : (t - 1))) * D_;
    bf16x8 bfr[32];
#pragma unroll
    for (int kk = 0; kk < 32; ++kk)
      bfr[kk] = *(const bf16x8*)(hsrc + kk * 32 + quad * 8);

    f32x4 acc0 = { (float)gxc[0], (float)gxc[1], (float)gxc[2], (float)gxc[3] };
    f32x4 acc1 = { 0.f, 0.f, 0.f, 0.f };
#pragma unroll
    for (int kk = 0; kk < 32; kk += 2) {
      acc0 = MFMA(wf[kk],     bfr[kk],     acc0);
      acc1 = MFMA(wf[kk + 1], bfr[kk + 1], acc1);
    }
    const f32x4 g = acc0 + acc1;
#pragma unroll
    for (int r = 0; r < 4; ++r) gbuf[wave][quad * 4 + r][l16] = g[r];
    __syncthreads();

    if (t0 < 128) {
      const int d = t0 >> 3, bb = t0 & 7;
      const float gi = gbuf[0][d][bb], gf = gbuf[1][d][bb];
      const float gg = gbuf[2][d][bb], go = gbuf[3][d][bb];
      float c = cst[d][bb];
      c = sigm(gf) * c + sigm(gi) * tanhf_(gg);
      const float h = sigm(go) * tanhf_(c);
      cst[d][bb] = c;
      H[((size_t)bb * SP_ + t) * D_ + ds + d] = (__bf16)h;
      if (t == SP_ - 1) {
        cc[(size_t)bb * 1024 + ds + d] = c;
        if (last) {
          dout[hoff + (size_t)bb * D_ + ds + d] = h;
          dout[coff + (size_t)bb * D_ + ds + d] = c;
        }
      }
    }
    __threadfence();   // release h stores
    grid.sync();
    __threadfence();   // acquire other XCDs' h stores
  }
}

// ---------------------------------------------------------------------------
// Kernel 3: out = relu(Hphase @ W1^T + b1) @ W2^T + b2.  64 rows per WG.
// Phase rows r = b*128 + sl  ->  out rows b*2048 + s0 + sl.
// ---------------------------------------------------------------------------
template <int OUTD>
__global__ __launch_bounds__(256, 2) void mlp_out(
    const __bf16* __restrict__ Hs, int s0,                        // 1024 x 1024 phase
    const __bf16* __restrict__ W1, const float* __restrict__ b1,  // 64x1024 bf16, 64 f32
    const __bf16* __restrict__ W2, const float* __restrict__ b2,  // OUTDx64 bf16, OUTD f32
    float* __restrict__ out)                                      // 16384 x OUTD f32
{
  const int r0    = blockIdx.x * 64;                  // phase-local row tile
  const int orow0 = (r0 >> 7) * S_ + s0 + (r0 & 127);
  const int t0   = threadIdx.x;
  const int wave = t0 >> 6;
  const int lane = t0 & 63;
  const int quad = lane >> 4;
  const int l16  = lane & 15;

  __shared__ __align__(16) __bf16 T[64][72];

  // Stage 1: T = relu(H_rows @ W1^T + b1); wave handles m-tile = wave.
  f32x4 a1[4];
#pragma unroll
  for (int nt = 0; nt < 4; ++nt) a1[nt] = (f32x4){0.f, 0.f, 0.f, 0.f};
  for (int kk = 0; kk < 32; ++kk) {
    const bf16x8 a = *(const bf16x8*)&Hs[(size_t)(r0 + wave * 16 + l16) * 1024 + kk * 32 + quad * 8];
#pragma unroll
    for (int nt = 0; nt < 4; ++nt) {
      const bf16x8 bb = *(const bf16x8*)&W1[(size_t)(nt * 16 + l16) * 1024 + kk * 32 + quad * 8];
      a1[nt] = MFMA(a, bb, a1[nt]);
    }
  }
#pragma unroll
  for (int nt = 0; nt < 4; ++nt) {
    const int n = nt * 16 + l16;
    const float bias = b1[n];
#pragma unroll
    for (int r = 0; r < 4; ++r)
      T[wave * 16 + quad * 4 + r][n] = (__bf16)fmaxf(a1[nt][r] + bias, 0.f);
  }
  __syncthreads();

  // Stage 2: out = T @ W2^T + b2; wave handles cols [wave*OUTD/4, ...).
  const int nw0 = wave * (OUTD / 4);
#pragma unroll
  for (int nt = 0; nt < OUTD / 64; ++nt) {
    f32x4 a2[4];
#pragma unroll
    for (int mt = 0; mt < 4; ++mt) a2[mt] = (f32x4){0.f, 0.f, 0.f, 0.f};
#pragma unroll
    for (int kk = 0; kk < 2; ++kk) {
      const bf16x8 bb = *(const bf16x8*)&W2[(size_t)(nw0 + nt * 16 + l16) * 64 + kk * 32 + quad * 8];
#pragma unroll
      for (int mt = 0; mt < 4; ++mt) {
        const bf16x8 a = *(const bf16x8*)&T[mt * 16 + l16][kk * 32 + quad * 8];
        a2[mt] = MFMA(a, bb, a2[mt]);
      }
    }
    const int n = nw0 + nt * 16 + l16;
    const float bias = b2[n];
#pragma unroll
    for (int mt = 0; mt < 4; ++mt)
#pragma unroll
      for (int r = 0; r < 4; ++r)
        out[(size_t)(orow0 + mt * 16 + quad * 4 + r) * OUTD + n] = a2[mt][r] + bias;
  }
}

// ---------------------------------------------------------------------------
extern "C" void kernel_launch(void* const* d_in, const int* in_sizes, int n_in,
                              void* d_out, int out_size, void* d_ws, size_t ws_size,
                              hipStream_t stream) {
  const float* x   = (const float*)d_in[0];
  const float* hq0 = (const float*)d_in[1];
  const float* cq0 = (const float*)d_in[2];
  const float* hk0 = (const float*)d_in[3];
  const float* ck0 = (const float*)d_in[4];
  const float* Wiq = (const float*)d_in[5];
  const float* Whq = (const float*)d_in[6];
  const float* biq = (const float*)d_in[7];
  const float* bhq = (const float*)d_in[8];
  const float* Wik = (const float*)d_in[9];
  const float* Whk = (const float*)d_in[10];
  const float* bik = (const float*)d_in[11];
  const float* bhk = (const float*)d_in[12];
  const float* W1q = (const float*)d_in[13];
  const float* b1q = (const float*)d_in[14];
  const float* W2q = (const float*)d_in[15];
  const float* b2q = (const float*)d_in[16];
  const float* W1k = (const float*)d_in[17];
  const float* b1k = (const float*)d_in[18];
  const float* W2k = (const float*)d_in[19];
  const float* b2k = (const float*)d_in[20];
  float* out = (float*)d_out;

  // Scratch layout (bytes), total ~38.9 MB:
  //   Whqb 8 MiB | Whkb 8 MiB | W1qb/W2qb/W1kb/W2kb ~0.4 MiB |
  //   GXq 8 MiB | GXk 8 MiB | Hq 2 MiB | Hk 2 MiB | Cc 64 KiB
  char* ws = (char*)d_ws;
  __bf16* Whqb = (__bf16*)(ws);
  __bf16* Whkb = (__bf16*)(ws + 8388608ul);
  __bf16* W1qb = (__bf16*)(ws + 16777216ul);
  __bf16* W2qb = (__bf16*)(ws + 16908288ul);
  __bf16* W1kb = (__bf16*)(ws + 17039360ul);
  __bf16* W2kb = (__bf16*)(ws + 17170432ul);
  __bf16* GXq  = (__bf16*)(ws + 17825792ul);
  __bf16* GXk  = (__bf16*)(ws + 26214400ul);
  __bf16* Hq   = (__bf16*)(ws + 34603008ul);
  __bf16* Hk   = (__bf16*)(ws + 36700160ul);
  float*  Cc   = (float*)(ws + 38797312ul);

  cast_bf16<<<dim3(2048), 256, 0, stream>>>(Whq, Whqb, 4194304);
  cast_bf16<<<dim3(2048), 256, 0, stream>>>(Whk, Whkb, 4194304);
  cast_bf16<<<dim3(64),   256, 0, stream>>>(W1q, W1qb, 65536);
  cast_bf16<<<dim3(64),   256, 0, stream>>>(W2q, W2qb, 65536);
  cast_bf16<<<dim3(64),   256, 0, stream>>>(W1k, W1kb, 65536);
  cast_bf16<<<dim3(16),   256, 0, stream>>>(W2k, W2kb, 16384);
  init_carry<<<dim3(64),  256, 0, stream>>>(hq0, cq0, hk0, ck0, Hq, Hk, Cc);

  for (int p = 0; p < NP_; ++p) {
    const int s0 = p * SP_;
    const int last = (p == NP_ - 1) ? 1 : 0;

    gemm_gx<<<dim3(32, 8, 2), 256, 0, stream>>>(x, s0, Wiq, biq, bhq, Wik, bik, bhk, GXq, GXk);

    const __bf16* aGXq = GXq; const __bf16* aGXk = GXk;
    const __bf16* aWhq = Whqb; const __bf16* aWhk = Whkb;
    __bf16* aHq = Hq; __bf16* aHk = Hk;
    float* aCc = Cc; float* aout = out; int alast = last;
    void* args[] = { &aGXq, &aGXk, &aWhq, &aWhk, &aHq, &aHk, &aCc, &aout, &alast };
    hipLaunchCooperativeKernel(reinterpret_cast<void*>(lstm_rec), dim3(128), dim3(256), args, 0, stream);

    mlp_out<1024><<<dim3(16), 256, 0, stream>>>(Hq, s0, W1qb, b1q, W2qb, b2q, out + OQ_OFF);
    mlp_out<256><<<dim3(16), 256, 0, stream>>>(Hk, s0, W1kb, b1k, W2kb, b2k, out + OK_OFF);
  }
}

// Round 4
// 13682.620 us; speedup vs baseline: 6.1151x; 6.1151x over previous
//
#include <hip/hip_runtime.h>
#include <hip/hip_cooperative_groups.h>

typedef __bf16 bf16x8 __attribute__((ext_vector_type(8)));
typedef __bf16 bf16x4 __attribute__((ext_vector_type(4)));
typedef float  f32x4  __attribute__((ext_vector_type(4)));
typedef unsigned long long u64;

#define MFMA(a, b, c) __builtin_amdgcn_mfma_f32_16x16x32_bf16((a), (b), (c), 0, 0, 0)

#define B_   8
#define S_   2048
#define SP_  128        // steps per phase
#define NP_  16         // phases
#define D_   1024
#define G4_  4096       // 4*D

// d_out ELEMENT offsets (f32 out)
#define OQ_OFF  0ul
#define OK_OFF  16777216ul
#define HQ_OFF  20971520ul
#define CQ_OFF  20979712ul
#define HK_OFF  20987904ul
#define CK_OFF  20996096ul

__device__ __forceinline__ float sigm(float x) { return 1.0f / (1.0f + __expf(-x)); }
__device__ __forceinline__ float tanhf_(float x) { return 1.0f - 2.0f / (1.0f + __expf(2.0f * x)); }

__device__ __forceinline__ bf16x8 cvt8(float4 a, float4 b) {
  bf16x8 r;
  r[0] = (__bf16)a.x; r[1] = (__bf16)a.y; r[2] = (__bf16)a.z; r[3] = (__bf16)a.w;
  r[4] = (__bf16)b.x; r[5] = (__bf16)b.y; r[6] = (__bf16)b.z; r[7] = (__bf16)b.w;
  return r;
}

// ---------------------------------------------------------------------------
// f32 -> bf16 cast (grid-stride)
// ---------------------------------------------------------------------------
__global__ void cast_bf16(const float* __restrict__ src, __bf16* __restrict__ dst, int n) {
  int i = blockIdx.x * 256 + threadIdx.x;
  const int stride = gridDim.x * 256;
  for (; i < n; i += stride) dst[i] = (__bf16)src[i];
}

// ---------------------------------------------------------------------------
// Init: seed h-carry (H row SP-1, bf16), c-carry (f32), zero barrier slots.
// ---------------------------------------------------------------------------
__global__ void init_carry(const float* __restrict__ hq0, const float* __restrict__ cq0,
                           const float* __restrict__ hk0, const float* __restrict__ ck0,
                           __bf16* __restrict__ Hq, __bf16* __restrict__ Hk,
                           float* __restrict__ Cc, unsigned int* __restrict__ bar) {
  const int idx  = blockIdx.x * 256 + threadIdx.x;   // 0..16383
  if (idx < 128) bar[idx] = 0u;
  const int cell = idx >> 13;
  const int rem  = idx & 8191;
  const int b    = rem >> 10;
  const int d    = rem & 1023;
  const float* h0 = cell ? hk0 : hq0;
  const float* c0 = cell ? ck0 : cq0;
  __bf16* H       = cell ? Hk  : Hq;
  H[((size_t)b * SP_ + (SP_ - 1)) * D_ + d] = (__bf16)h0[(size_t)b * D_ + d];
  Cc[(size_t)cell * 8192 + b * 1024 + d]    = c0[(size_t)b * D_ + d];
}

// ---------------------------------------------------------------------------
// Kernel 1: phase gx = x_phase @ Wi^T + (bi + bh), both cells (blockIdx.z).
// f32 inputs, converted to bf16 during manual LDS staging. m97 MFMA core.
// ---------------------------------------------------------------------------
__global__ __launch_bounds__(256, 2) void gemm_gx(
    const float* __restrict__ X, int s0,
    const float* __restrict__ Wq, const float* __restrict__ biq, const float* __restrict__ bhq,
    const float* __restrict__ Wk, const float* __restrict__ bik, const float* __restrict__ bhk,
    __bf16* __restrict__ GXq, __bf16* __restrict__ GXk)
{
  const float* W;  const float* bi;  const float* bh;  __bf16* GX;
  if (blockIdx.z == 0) { W = Wq; bi = biq; bh = bhq; GX = GXq; }
  else                 { W = Wk; bi = bik; bh = bhk; GX = GXk; }

  const int m0 = blockIdx.y * 128;                 // phase-local row tile
  const int n0 = blockIdx.x * 128;
  const int xrow0 = (m0 >> 7) * S_ + s0;           // 128 rows contiguous in X

  __shared__ __align__(16) __bf16 As[128 * 32];
  __shared__ __align__(16) __bf16 Bs[128 * 32];

  const int t    = threadIdx.x;
  const int wave = t >> 6;
  const int lane = t & 63;
  const int quad = lane >> 4;
  const int l16  = lane & 15;
  const int srow = t >> 1;
  const int scol = (t & 1) * 16;
  const int wm = wave & 1, wn = wave >> 1;

  f32x4 acc[4][4];
#pragma unroll
  for (int i = 0; i < 4; ++i)
#pragma unroll
    for (int j = 0; j < 4; ++j) acc[i][j] = (f32x4){0.f, 0.f, 0.f, 0.f};

  for (int kk = 0; kk < 1024; kk += 32) {
    const float* ga = X + (size_t)(xrow0 + srow) * 1024 + kk + scol;
    const float* gb = W + (size_t)(n0 + srow) * 1024 + kk + scol;
    const float4 va0 = *(const float4*)(ga);     const float4 va1 = *(const float4*)(ga + 4);
    const float4 va2 = *(const float4*)(ga + 8); const float4 va3 = *(const float4*)(ga + 12);
    const float4 vb0 = *(const float4*)(gb);     const float4 vb1 = *(const float4*)(gb + 4);
    const float4 vb2 = *(const float4*)(gb + 8); const float4 vb3 = *(const float4*)(gb + 12);
    __syncthreads();
    *(bf16x8*)&As[srow * 32 + scol]     = cvt8(va0, va1);
    *(bf16x8*)&As[srow * 32 + scol + 8] = cvt8(va2, va3);
    *(bf16x8*)&Bs[srow * 32 + scol]     = cvt8(vb0, vb1);
    *(bf16x8*)&Bs[srow * 32 + scol + 8] = cvt8(vb2, vb3);
    __syncthreads();

    bf16x8 af[4], bfq[4];
#pragma unroll
    for (int i = 0; i < 4; ++i) af[i]  = *(const bf16x8*)&As[(wm * 64 + i * 16 + l16) * 32 + quad * 8];
#pragma unroll
    for (int j = 0; j < 4; ++j) bfq[j] = *(const bf16x8*)&Bs[(wn * 64 + j * 16 + l16) * 32 + quad * 8];
#pragma unroll
    for (int i = 0; i < 4; ++i)
#pragma unroll
      for (int j = 0; j < 4; ++j)
        acc[i][j] = MFMA(af[i], bfq[j], acc[i][j]);
  }

#pragma unroll
  for (int j = 0; j < 4; ++j) {
    const int n = n0 + wn * 64 + j * 16 + l16;
    const float bias = bi[n] + bh[n];
#pragma unroll
    for (int i = 0; i < 4; ++i) {
#pragma unroll
      for (int r = 0; r < 4; ++r) {
        const int m = m0 + wm * 64 + i * 16 + quad * 4 + r;
        GX[(size_t)m * G4_ + n] = (__bf16)(acc[i][j][r] + bias);
      }
    }
  }
}

// ---------------------------------------------------------------------------
// Kernel 2: one phase (128 steps). 128 WGs x 256 thr (cooperative: residency).
// Cross-WG h exchange via agent-scope relaxed atomics (sc0 sc1 -> coherent
// point; no L2 writeback/invalidate instructions). Flat all-poll barrier:
// WG w publishes generation to bar[w]; every WG polls all 128 slots.
// ---------------------------------------------------------------------------
__global__ __launch_bounds__(256, 1) void lstm_rec(
    const __bf16* __restrict__ GXq, const __bf16* __restrict__ GXk,
    const __bf16* __restrict__ Whq, const __bf16* __restrict__ Whk,
    __bf16* __restrict__ Hq, __bf16* __restrict__ Hk,
    float* __restrict__ Cc, float* __restrict__ dout,
    unsigned int* __restrict__ bar, int s0, int last)
{
  const int wg   = blockIdx.x;           // 0..127
  const int cell = wg >> 6;
  const int ds   = (wg & 63) * 16;       // hidden-dim base
  const int t0   = threadIdx.x;
  const int wave = t0 >> 6;              // gate type: 0=i 1=f 2=g 3=o
  const int lane = t0 & 63;
  const int quad = lane >> 4;
  const int l16  = lane & 15;
  const int b    = l16 & 7;              // batch (cols 8..15 duplicate 0..7)

  const __bf16* GX = cell ? GXk : GXq;
  const __bf16* Wh = cell ? Whk : Whq;
  __bf16* H        = cell ? Hk  : Hq;
  float* cc        = Cc + (size_t)cell * 8192;
  const size_t hoff = cell ? HK_OFF : HQ_OFF;
  const size_t coff = cell ? CK_OFF : CQ_OFF;

  const int gbase = wave * 1024 + ds;

  // A-fragments of Wh, register-resident: A[m=l16][k=quad*8+j], 32 K-chunks.
  bf16x8 wf[32];
#pragma unroll
  for (int kk = 0; kk < 32; ++kk)
    wf[kk] = *(const bf16x8*)&Wh[(size_t)(gbase + l16) * 1024 + kk * 32 + quad * 8];

  __shared__ float gbuf[4][16][16];
  __shared__ float cst[16][8];
  __shared__ __align__(16) __bf16 hs[8 * 1032];   // h staged per WG, +8 pad/row

  if (t0 < 128) {
    const int d = t0 >> 3, bb = t0 & 7;
    cst[d][bb] = cc[(size_t)bb * 1024 + ds + d];
  }
  __syncthreads();

  const __bf16* gxlane = GX + (size_t)b * SP_ * G4_ + gbase + quad * 4;
  bf16x4 gxn = *(const bf16x4*)(gxlane);

  // h staging assignment: thread -> (batch hb, 64B chunk hc)
  const int hb = t0 >> 5;
  const int hc = t0 & 31;

  for (int t = 0; t < SP_; ++t) {
    const unsigned int g = (unsigned int)(s0 + t + 1);   // global generation
    const bf16x4 gxc = gxn;
    if (t < SP_ - 1) gxn = *(const bf16x4*)(gxlane + (size_t)(t + 1) * G4_);

    // ---- stage h_{t-1} into LDS (agent-scope loads, dedup via LDS) ----
    const int tprev = (t == 0) ? (SP_ - 1) : (t - 1);
    {
      const u64* hrow = (const u64*)(H + ((size_t)hb * SP_ + tprev) * D_) + hc * 8;
      u64 u[8];
#pragma unroll
      for (int j = 0; j < 8; ++j)
        u[j] = __hip_atomic_load(hrow + j, __ATOMIC_RELAXED, __HIP_MEMORY_SCOPE_AGENT);
#pragma unroll
      for (int j = 0; j < 8; ++j)
        *(u64*)&hs[hb * 1032 + hc * 32 + j * 4] = u[j];
    }
    __syncthreads();                                   // [A] hs ready

    // ---- MFMA: gates = Wh x h  (+gx) ----
    const __bf16* hrow_l = &hs[b * 1032];
    f32x4 acc0 = { (float)gxc[0], (float)gxc[1], (float)gxc[2], (float)gxc[3] };
    f32x4 acc1 = { 0.f, 0.f, 0.f, 0.f };
#pragma unroll
    for (int kk = 0; kk < 32; kk += 2) {
      const bf16x8 b0 = *(const bf16x8*)&hrow_l[kk * 32 + quad * 8];
      const bf16x8 b1 = *(const bf16x8*)&hrow_l[(kk + 1) * 32 + quad * 8];
      acc0 = MFMA(wf[kk],     b0, acc0);
      acc1 = MFMA(wf[kk + 1], b1, acc1);
    }
    const f32x4 gv = acc0 + acc1;
#pragma unroll
    for (int r = 0; r < 4; ++r) gbuf[wave][quad * 4 + r][l16] = gv[r];
    __syncthreads();                                   // [B] gbuf ready

    // ---- pointwise: 64 threads x 2 dims ----
    if (t0 < 64) {
      const int bb = t0 & 7, dp = t0 >> 3;
      unsigned int pack;
      float c_out[2];
#pragma unroll
      for (int e = 0; e < 2; ++e) {
        const int d = dp * 2 + e;
        const float gi = gbuf[0][d][bb], gf = gbuf[1][d][bb];
        const float gg = gbuf[2][d][bb], go = gbuf[3][d][bb];
        float c = cst[d][bb];
        c = sigm(gf) * c + sigm(gi) * tanhf_(gg);
        const float h = sigm(go) * tanhf_(c);
        cst[d][bb] = c;
        c_out[e] = c;
        union { __bf16 v; unsigned short s; } cvt; cvt.v = (__bf16)h;
        if (e == 0) pack = cvt.s; else pack |= ((unsigned int)cvt.s << 16);
        if (last && t == SP_ - 1) {
          dout[hoff + (size_t)bb * D_ + ds + d] = h;
          dout[coff + (size_t)bb * D_ + ds + d] = c;
        }
      }
      // h store: agent-scope, write-through to coherent point
      unsigned int* hp = (unsigned int*)(H + ((size_t)bb * SP_ + t) * D_ + ds + dp * 2);
      __hip_atomic_store(hp, pack, __ATOMIC_RELAXED, __HIP_MEMORY_SCOPE_AGENT);
      if (t == SP_ - 1) {
        cc[(size_t)bb * 1024 + ds + dp * 2]     = c_out[0];
        cc[(size_t)bb * 1024 + ds + dp * 2 + 1] = c_out[1];
      }
    }
    // drain own stores to the coherent point, then rendezvous
    __builtin_amdgcn_s_waitcnt(0);
    __syncthreads();                                   // [C] all WG stores drained

    if (t0 == 0)
      __hip_atomic_store(&bar[wg], g, __ATOMIC_RELAXED, __HIP_MEMORY_SCOPE_AGENT);
    if (t0 < 128) {
      while (__hip_atomic_load(&bar[t0], __ATOMIC_RELAXED, __HIP_MEMORY_SCOPE_AGENT) < g) {}
    }
    __atomic_signal_fence(__ATOMIC_SEQ_CST);
    __syncthreads();                                   // [D] barrier done
  }
}

// ---------------------------------------------------------------------------
// Kernel 3: out = relu(Hphase @ W1^T + b1) @ W2^T + b2.  64 rows per WG,
// 256 output cols per block (blockIdx.y).
// ---------------------------------------------------------------------------
template <int OUTD>
__global__ __launch_bounds__(256, 2) void mlp_out(
    const __bf16* __restrict__ Hs, int s0,
    const __bf16* __restrict__ W1, const float* __restrict__ b1,
    const __bf16* __restrict__ W2, const float* __restrict__ b2,
    float* __restrict__ out)
{
  const int r0    = blockIdx.x * 64;
  const int orow0 = (r0 >> 7) * S_ + s0 + (r0 & 127);
  const int t0   = threadIdx.x;
  const int wave = t0 >> 6;
  const int lane = t0 & 63;
  const int quad = lane >> 4;
  const int l16  = lane & 15;

  __shared__ __align__(16) __bf16 T[64][72];

  // Stage 1: T = relu(H_rows @ W1^T + b1)
  f32x4 a1[4];
#pragma unroll
  for (int nt = 0; nt < 4; ++nt) a1[nt] = (f32x4){0.f, 0.f, 0.f, 0.f};
  for (int kk = 0; kk < 32; ++kk) {
    const bf16x8 a = *(const bf16x8*)&Hs[(size_t)(r0 + wave * 16 + l16) * 1024 + kk * 32 + quad * 8];
#pragma unroll
    for (int nt = 0; nt < 4; ++nt) {
      const bf16x8 bb = *(const bf16x8*)&W1[(size_t)(nt * 16 + l16) * 1024 + kk * 32 + quad * 8];
      a1[nt] = MFMA(a, bb, a1[nt]);
    }
  }
#pragma unroll
  for (int nt = 0; nt < 4; ++nt) {
    const int n = nt * 16 + l16;
    const float bias = b1[n];
#pragma unroll
    for (int r = 0; r < 4; ++r)
      T[wave * 16 + quad * 4 + r][n] = (__bf16)fmaxf(a1[nt][r] + bias, 0.f);
  }
  __syncthreads();

  // Stage 2: 64 cols per wave within this block's 256-col slab.
  const int nw0 = blockIdx.y * 256 + wave * 64;
#pragma unroll
  for (int nt = 0; nt < 4; ++nt) {
    f32x4 a2[4];
#pragma unroll
    for (int mt = 0; mt < 4; ++mt) a2[mt] = (f32x4){0.f, 0.f, 0.f, 0.f};
#pragma unroll
    for (int kk = 0; kk < 2; ++kk) {
      const bf16x8 bb = *(const bf16x8*)&W2[(size_t)(nw0 + nt * 16 + l16) * 64 + kk * 32 + quad * 8];
#pragma unroll
      for (int mt = 0; mt < 4; ++mt) {
        const bf16x8 a = *(const bf16x8*)&T[mt * 16 + l16][kk * 32 + quad * 8];
        a2[mt] = MFMA(a, bb, a2[mt]);
      }
    }
    const int n = nw0 + nt * 16 + l16;
    const float bias = b2[n];
#pragma unroll
    for (int mt = 0; mt < 4; ++mt)
#pragma unroll
      for (int r = 0; r < 4; ++r)
        out[(size_t)(orow0 + mt * 16 + quad * 4 + r) * OUTD + n] = a2[mt][r] + bias;
  }
}

// ---------------------------------------------------------------------------
extern "C" void kernel_launch(void* const* d_in, const int* in_sizes, int n_in,
                              void* d_out, int out_size, void* d_ws, size_t ws_size,
                              hipStream_t stream) {
  const float* x   = (const float*)d_in[0];
  const float* hq0 = (const float*)d_in[1];
  const float* cq0 = (const float*)d_in[2];
  const float* hk0 = (const float*)d_in[3];
  const float* ck0 = (const float*)d_in[4];
  const float* Wiq = (const float*)d_in[5];
  const float* Whq = (const float*)d_in[6];
  const float* biq = (const float*)d_in[7];
  const float* bhq = (const float*)d_in[8];
  const float* Wik = (const float*)d_in[9];
  const float* Whk = (const float*)d_in[10];
  const float* bik = (const float*)d_in[11];
  const float* bhk = (const float*)d_in[12];
  const float* W1q = (const float*)d_in[13];
  const float* b1q = (const float*)d_in[14];
  const float* W2q = (const float*)d_in[15];
  const float* b2q = (const float*)d_in[16];
  const float* W1k = (const float*)d_in[17];
  const float* b1k = (const float*)d_in[18];
  const float* W2k = (const float*)d_in[19];
  const float* b2k = (const float*)d_in[20];
  float* out = (float*)d_out;

  // Scratch layout (~38.9 MB)
  char* ws = (char*)d_ws;
  __bf16* Whqb = (__bf16*)(ws);
  __bf16* Whkb = (__bf16*)(ws + 8388608ul);
  __bf16* W1qb = (__bf16*)(ws + 16777216ul);
  __bf16* W2qb = (__bf16*)(ws + 16908288ul);
  __bf16* W1kb = (__bf16*)(ws + 17039360ul);
  __bf16* W2kb = (__bf16*)(ws + 17170432ul);
  __bf16* GXq  = (__bf16*)(ws + 17825792ul);
  __bf16* GXk  = (__bf16*)(ws + 26214400ul);
  __bf16* Hq   = (__bf16*)(ws + 34603008ul);
  __bf16* Hk   = (__bf16*)(ws + 36700160ul);
  float*  Cc   = (float*)(ws + 38797312ul);
  unsigned int* bar = (unsigned int*)(ws + 38862848ul);

  cast_bf16<<<dim3(2048), 256, 0, stream>>>(Whq, Whqb, 4194304);
  cast_bf16<<<dim3(2048), 256, 0, stream>>>(Whk, Whkb, 4194304);
  cast_bf16<<<dim3(64),   256, 0, stream>>>(W1q, W1qb, 65536);
  cast_bf16<<<dim3(64),   256, 0, stream>>>(W2q, W2qb, 65536);
  cast_bf16<<<dim3(64),   256, 0, stream>>>(W1k, W1kb, 65536);
  cast_bf16<<<dim3(16),   256, 0, stream>>>(W2k, W2kb, 16384);
  init_carry<<<dim3(64),  256, 0, stream>>>(hq0, cq0, hk0, ck0, Hq, Hk, Cc, bar);

  for (int p = 0; p < NP_; ++p) {
    const int s0 = p * SP_;
    const int last = (p == NP_ - 1) ? 1 : 0;

    gemm_gx<<<dim3(32, 8, 2), 256, 0, stream>>>(x, s0, Wiq, biq, bhq, Wik, bik, bhk, GXq, GXk);

    const __bf16* aGXq = GXq; const __bf16* aGXk = GXk;
    const __bf16* aWhq = Whqb; const __bf16* aWhk = Whkb;
    __bf16* aHq = Hq; __bf16* aHk = Hk;
    float* aCc = Cc; float* aout = out;
    unsigned int* abar = bar; int as0 = s0; int alast = last;
    void* args[] = { &aGXq, &aGXk, &aWhq, &aWhk, &aHq, &aHk, &aCc, &aout, &abar, &as0, &alast };
    hipLaunchCooperativeKernel(reinterpret_cast<void*>(lstm_rec), dim3(128), dim3(256), args, 0, stream);

    mlp_out<1024><<<dim3(16, 4), 256, 0, stream>>>(Hq, s0, W1qb, b1q, W2qb, b2q, out + OQ_OFF);
    mlp_out<256><<<dim3(16, 1), 256, 0, stream>>>(Hk, s0, W1kb, b1k, W2kb, b2k, out + OK_OFF);
  }
}